// Round 4
// baseline (332.934 us; speedup 1.0000x reference)
//
#include <hip/hip_runtime.h>
#include <hip/hip_bf16.h>

// NT-Xent loss, MI355X, round 4.
//  k_prep     : fused fp32 row-norms + bf16 normalize + exact positives (+zero out)
//  k_flash    : sim = zn@zn^T via MFMA bf16, fixed-max LSE (logits<=2),
//               double-buffered async staging, software-pipelined epilogue:
//               MFMA(tile ct) interleaved with exp-epilogue(tile ct-1)
//  k_finalize : 32 blocks, wave reduce + atomicAdd

#define B_ 4096
#define N_ 8192
#define D_ 256
#define EPS_ 1e-8f
#define SPLITS 16
#define BM 128              // rows per block (4 waves x 32 rows)
#define BN 32               // cols per LDS tile
#define KC 8                // D/32 k-chunks
#define CPS (N_ / SPLITS)   // 512 cols per split
#define NT_ (CPS / BN)      // 16 tiles per split
#define LOG2E 1.44269504088896340736f

typedef __attribute__((ext_vector_type(8))) short bfrag_t;   // 8 bf16
typedef __attribute__((ext_vector_type(4))) float f32x4_t;   // MFMA C/D

__device__ __forceinline__ ushort f2bf_rne(float x) {
  union { float f; unsigned u; } a; a.f = x;
  unsigned r = a.u + 0x7FFFu + ((a.u >> 16) & 1u);
  return (ushort)(r >> 16);
}

__device__ __forceinline__ void cp16_lds(const uint4* g, uint4* l) {
  __builtin_amdgcn_global_load_lds(
      (const __attribute__((address_space(1))) unsigned int*)g,
      (__attribute__((address_space(3))) unsigned int*)l, 16, 0, 0);
}

// ---------------- fused normalize + positives: one wave per pair ----------------
__global__ __launch_bounds__(256) void k_prep(
    const float* __restrict__ zi, const float* __restrict__ zj,
    ushort* __restrict__ zn, float* __restrict__ pos, float* __restrict__ out) {
  if (blockIdx.x == 0 && threadIdx.x == 0) out[0] = 0.0f;  // for finalize atomics
  const int w = threadIdx.x >> 6, lane = threadIdx.x & 63;
  const int p = blockIdx.x * 4 + w;
  float4 a = reinterpret_cast<const float4*>(zi + (size_t)p * D_)[lane];
  float4 b = reinterpret_cast<const float4*>(zj + (size_t)p * D_)[lane];
  float si = a.x * a.x + a.y * a.y + a.z * a.z + a.w * a.w;
  float sj = b.x * b.x + b.y * b.y + b.z * b.z + b.w * b.w;
  float dd = a.x * b.x + a.y * b.y + a.z * b.z + a.w * b.w;
#pragma unroll
  for (int d = 1; d < 64; d <<= 1) {
    si += __shfl_xor(si, d);
    sj += __shfl_xor(sj, d);
    dd += __shfl_xor(dd, d);
  }
  const float ni = fmaxf(sqrtf(si), EPS_), nj = fmaxf(sqrtf(sj), EPS_);
  const float ii = 1.0f / ni, ij = 1.0f / nj;
  ushort4 oi, oj;
  oi.x = f2bf_rne(a.x * ii); oi.y = f2bf_rne(a.y * ii);
  oi.z = f2bf_rne(a.z * ii); oi.w = f2bf_rne(a.w * ii);
  oj.x = f2bf_rne(b.x * ij); oj.y = f2bf_rne(b.y * ij);
  oj.z = f2bf_rne(b.z * ij); oj.w = f2bf_rne(b.w * ij);
  reinterpret_cast<ushort4*>(zn + (size_t)p * D_)[lane] = oi;
  reinterpret_cast<ushort4*>(zn + (size_t)(p + B_) * D_)[lane] = oj;
  if (lane == 0) {
    float v = dd / (ni * nj) * 2.0f;   // /T with T=0.5
    pos[p] = v;
    pos[p + B_] = v;
  }
}

// ---------------- flash LSE (fixed max = 2), pipelined epilogue ----------------
__global__ __launch_bounds__(256, 4) void k_flash(
    const ushort* __restrict__ zn, const int* __restrict__ labels,
    float* __restrict__ Spart) {
  __shared__ uint4 lds16[2 * BN * 32];   // 2 x 16KB tile buffers, swizzled
  __shared__ int labbuf[CPS];            // this split's column labels, 2KB
  const int tid = threadIdx.x;
  const int w = tid >> 6, lane = tid & 63;
  const int l15 = lane & 15, l4 = lane >> 4;
  const int c31 = lane & 31, lh = lane >> 5;

  // XCD-aware bijective swizzle: XCD x gets splits {2x,2x+1} x 64 row-blocks
  const int bid = blockIdx.x;
  const int swz = (bid & 7) * 128 + (bid >> 3);
  const int rowblk = swz & 63, split = swz >> 6;
  const int arowb = rowblk * BM + w * 32;

  // A fragments: 32 rows x 256 K in registers for the whole block.
  bfrag_t a[2][KC];
#pragma unroll
  for (int mf = 0; mf < 2; ++mf) {
    const int ar = arowb + mf * 16 + l15;
#pragma unroll
    for (int kc = 0; kc < KC; ++kc)
      a[mf][kc] = *reinterpret_cast<const bfrag_t*>(
          zn + (size_t)ar * D_ + kc * 32 + l4 * 8);
  }

  labbuf[tid]       = labels[(split * CPS + tid) & (B_ - 1)];
  labbuf[tid + 256] = labels[(split * CPS + tid + 256) & (B_ - 1)];

  int labR[2][4];
#pragma unroll
  for (int mf = 0; mf < 2; ++mf)
#pragma unroll
    for (int rg = 0; rg < 4; ++rg)
      labR[mf][rg] = labels[(arowb + mf * 16 + l4 * 4 + rg) & (B_ - 1)];

  float Srun[2][4];
#pragma unroll
  for (int mf = 0; mf < 2; ++mf)
#pragma unroll
    for (int rg = 0; rg < 4; ++rg) Srun[mf][rg] = 0.f;

  // hoisted addressing ----------------------------------------------------
  const int offp0 = l15 * 512 + ((l4 ^ (l15 & 7)) << 4);
  const int offp1 = l15 * 512 + (((4 + l4) ^ (l15 & 7)) << 4);
  uint so[4];
#pragma unroll
  for (int q = 0; q < 4; ++q) {
    const int rw = w * 8 + q * 2 + lh;
    so[q] = rw * 32 + (c31 ^ (rw & 7));
  }
  const uint4* gsplit =
      reinterpret_cast<const uint4*>(zn) + (size_t)(split * CPS) * 32;
  const char* lb0 = (const char*)lds16;
  const char* lb1 = (const char*)lds16 + (1 << 14);

  auto stage = [&](int t, int bufsel) {
    const uint4* gt = gsplit + t * (BN * 32);
    uint4* db = lds16 + bufsel * (BN * 32) + w * 256;
#pragma unroll
    for (int q = 0; q < 4; ++q) cp16_lds(gt + so[q], db + q * 64);
  };

  auto mfma_tile = [&](const char* lb, f32x4_t (&acc)[2][2]) {
#pragma unroll
    for (int mf = 0; mf < 2; ++mf)
#pragma unroll
      for (int nf = 0; nf < 2; ++nf)
        acc[mf][nf] = (f32x4_t){0.f, 0.f, 0.f, 0.f};
#pragma unroll
    for (int kc = 0; kc < KC; ++kc) {
      const int kimm = (kc >> 1) << 7;
      const int po = (kc & 1) ? offp1 : offp0;
#pragma unroll
      for (int nf = 0; nf < 2; ++nf) {
        bfrag_t bf = *reinterpret_cast<const bfrag_t*>(lb + po + nf * 8192 + kimm);
        acc[0][nf] = __builtin_amdgcn_mfma_f32_16x16x32_bf16(a[0][kc], bf, acc[0][nf], 0, 0, 0);
        acc[1][nf] = __builtin_amdgcn_mfma_f32_16x16x32_bf16(a[1][kc], bf, acc[1][nf], 0, 0, 0);
      }
    }
  };

  // fixed-max epilogue for a finished tile: S += exp(sim*2 - 2), label-masked
  auto epi = [&](int ct, f32x4_t (&acc)[2][2]) {
    const int lc0 = labbuf[ct * BN + l15];
    const int lc1 = labbuf[ct * BN + 16 + l15];
#pragma unroll
    for (int mf = 0; mf < 2; ++mf) {
#pragma unroll
      for (int rg = 0; rg < 4; ++rg) {
        const int rl = labR[mf][rg];
        float t0 = fmaf(acc[mf][0][rg], 2.0f * LOG2E, -2.0f * LOG2E);
        float t1 = fmaf(acc[mf][1][rg], 2.0f * LOG2E, -2.0f * LOG2E);
        float e0 = __builtin_amdgcn_exp2f(t0);
        float e1 = __builtin_amdgcn_exp2f(t1);
        e0 = (lc0 != rl) ? e0 : 0.0f;
        e1 = (lc1 != rl) ? e1 : 0.0f;
        Srun[mf][rg] += e0 + e1;
      }
    }
  };

  f32x4_t accA[2][2], accB[2][2];

  // pipeline: MFMA(ct) overlaps epi(ct-1); barrier per tile as before.
  stage(0, 0);
  __syncthreads();                 // buf0 + labbuf ready
  stage(1, 1);
  mfma_tile(lb0, accA);            // tile 0
  __syncthreads();                 // drains stage(1); frees nothing yet

#pragma unroll
  for (int c2 = 0; c2 < (NT_ - 2) / 2; ++c2) {   // 7 pairs: tiles 1..14
    const int ct = 1 + 2 * c2;
    stage(ct + 1, 0);              // refill buf0 (tile ct-1's readers done)
    mfma_tile(lb1, accB);          // tile ct   (odd -> buf1)
    epi(ct - 1, accA);             // overlapped VALU
    __syncthreads();
    stage(ct + 2, 1);              // ct+2 <= 15 always in this loop
    mfma_tile(lb0, accA);          // tile ct+1 (even -> buf0)
    epi(ct, accB);
    __syncthreads();
  }
  mfma_tile(lb1, accB);            // tile 15
  epi(NT_ - 2, accA);
  epi(NT_ - 1, accB);

  // cross-lane (16 cols) sum, one write per row per split
#pragma unroll
  for (int mf = 0; mf < 2; ++mf) {
#pragma unroll
    for (int rg = 0; rg < 4; ++rg) {
      float s = Srun[mf][rg];
#pragma unroll
      for (int d = 1; d < 16; d <<= 1) s += __shfl_xor(s, d);
      if (l15 == 0)
        Spart[(size_t)split * N_ + arowb + mf * 16 + l4 * 4 + rg] = s;
    }
  }
}

// ---------------- finalize: 32 blocks, atomic ----------------
__global__ __launch_bounds__(256) void k_finalize(
    const float* __restrict__ Spart, const float* __restrict__ pos,
    float* __restrict__ out) {
  __shared__ float red[4];
  const int i = blockIdx.x * 256 + threadIdx.x;
  const float p = pos[i];
  float S = __builtin_amdgcn_exp2f(fmaf(p, LOG2E, -2.0f * LOG2E));  // exp(p-2)
#pragma unroll
  for (int s = 0; s < SPLITS; ++s) S += Spart[s * N_ + i];
  float c = 2.0f + __logf(S) - p;   // lse_i - pos_i
#pragma unroll
  for (int d = 1; d < 64; d <<= 1) c += __shfl_xor(c, d);
  const int w = threadIdx.x >> 6, lane = threadIdx.x & 63;
  if (lane == 0) red[w] = c;
  __syncthreads();
  if (threadIdx.x == 0) {
    float t = red[0] + red[1] + red[2] + red[3];
    atomicAdd(out, t * (1.0f / (float)N_));
  }
}

extern "C" void kernel_launch(void* const* d_in, const int* in_sizes, int n_in,
                              void* d_out, int out_size, void* d_ws, size_t ws_size,
                              hipStream_t stream) {
  (void)in_sizes; (void)n_in; (void)out_size; (void)ws_size;
  const float* zi = (const float*)d_in[0];
  const float* zj = (const float*)d_in[1];
  const int* labels = (const int*)d_in[2];
  char* ws = (char*)d_ws;
  ushort* zn   = (ushort*)(ws);                               // 4 MB
  float* pos   = (float*)(ws + 4u * 1024 * 1024);             // 32 KB
  float* Spart = (float*)(ws + 4u * 1024 * 1024 + 32 * 1024); // 512 KB
  float* out = (float*)d_out;

  k_prep<<<B_ / 4, 256, 0, stream>>>(zi, zj, zn, pos, out);
  k_flash<<<(N_ / BM) * SPLITS, 256, 0, stream>>>(zn, labels, Spart);
  k_finalize<<<N_ / 256, 256, 0, stream>>>(Spart, pos, out);
}

// Round 5
// 164.230 us; speedup vs baseline: 2.0272x; 2.0272x over previous
//
#include <hip/hip_runtime.h>
#include <hip/hip_bf16.h>

// NT-Xent loss, MI355X, round 5.
// Round-4 structure, but launch_bounds relaxed (256,4)->(256,2): round 4's
// regression was VGPR-cap spill traffic (456MB fetch / 416MB write scratch),
// not the pipeline. One variable changed.
//  k_prep     : fused fp32 row-norms + bf16 normalize + exact positives (+zero out)
//  k_flash    : sim = zn@zn^T via MFMA bf16, fixed-max LSE (logits<=2),
//               double-buffered async staging, software-pipelined epilogue
//  k_finalize : 32 blocks, wave reduce + atomicAdd

#define B_ 4096
#define N_ 8192
#define D_ 256
#define EPS_ 1e-8f
#define SPLITS 16
#define BM 128              // rows per block (4 waves x 32 rows)
#define BN 32               // cols per LDS tile
#define KC 8                // D/32 k-chunks
#define CPS (N_ / SPLITS)   // 512 cols per split
#define NT_ (CPS / BN)      // 16 tiles per split
#define LOG2E 1.44269504088896340736f

typedef __attribute__((ext_vector_type(8))) short bfrag_t;   // 8 bf16
typedef __attribute__((ext_vector_type(4))) float f32x4_t;   // MFMA C/D

__device__ __forceinline__ ushort f2bf_rne(float x) {
  union { float f; unsigned u; } a; a.f = x;
  unsigned r = a.u + 0x7FFFu + ((a.u >> 16) & 1u);
  return (ushort)(r >> 16);
}

__device__ __forceinline__ void cp16_lds(const uint4* g, uint4* l) {
  __builtin_amdgcn_global_load_lds(
      (const __attribute__((address_space(1))) unsigned int*)g,
      (__attribute__((address_space(3))) unsigned int*)l, 16, 0, 0);
}

// ---------------- fused normalize + positives: one wave per pair ----------------
__global__ __launch_bounds__(256) void k_prep(
    const float* __restrict__ zi, const float* __restrict__ zj,
    ushort* __restrict__ zn, float* __restrict__ pos, float* __restrict__ out) {
  if (blockIdx.x == 0 && threadIdx.x == 0) out[0] = 0.0f;  // for finalize atomics
  const int w = threadIdx.x >> 6, lane = threadIdx.x & 63;
  const int p = blockIdx.x * 4 + w;
  float4 a = reinterpret_cast<const float4*>(zi + (size_t)p * D_)[lane];
  float4 b = reinterpret_cast<const float4*>(zj + (size_t)p * D_)[lane];
  float si = a.x * a.x + a.y * a.y + a.z * a.z + a.w * a.w;
  float sj = b.x * b.x + b.y * b.y + b.z * b.z + b.w * b.w;
  float dd = a.x * b.x + a.y * b.y + a.z * b.z + a.w * b.w;
#pragma unroll
  for (int d = 1; d < 64; d <<= 1) {
    si += __shfl_xor(si, d);
    sj += __shfl_xor(sj, d);
    dd += __shfl_xor(dd, d);
  }
  const float ni = fmaxf(sqrtf(si), EPS_), nj = fmaxf(sqrtf(sj), EPS_);
  const float ii = 1.0f / ni, ij = 1.0f / nj;
  ushort4 oi, oj;
  oi.x = f2bf_rne(a.x * ii); oi.y = f2bf_rne(a.y * ii);
  oi.z = f2bf_rne(a.z * ii); oi.w = f2bf_rne(a.w * ii);
  oj.x = f2bf_rne(b.x * ij); oj.y = f2bf_rne(b.y * ij);
  oj.z = f2bf_rne(b.z * ij); oj.w = f2bf_rne(b.w * ij);
  reinterpret_cast<ushort4*>(zn + (size_t)p * D_)[lane] = oi;
  reinterpret_cast<ushort4*>(zn + (size_t)(p + B_) * D_)[lane] = oj;
  if (lane == 0) {
    float v = dd / (ni * nj) * 2.0f;   // /T with T=0.5
    pos[p] = v;
    pos[p + B_] = v;
  }
}

// ---------------- flash LSE (fixed max = 2), pipelined epilogue ----------------
__global__ __launch_bounds__(256, 2) void k_flash(
    const ushort* __restrict__ zn, const int* __restrict__ labels,
    float* __restrict__ Spart) {
  __shared__ uint4 lds16[2 * BN * 32];   // 2 x 16KB tile buffers, swizzled
  __shared__ int labbuf[CPS];            // this split's column labels, 2KB
  const int tid = threadIdx.x;
  const int w = tid >> 6, lane = tid & 63;
  const int l15 = lane & 15, l4 = lane >> 4;
  const int c31 = lane & 31, lh = lane >> 5;

  // XCD-aware bijective swizzle: XCD x gets splits {2x,2x+1} x 64 row-blocks
  const int bid = blockIdx.x;
  const int swz = (bid & 7) * 128 + (bid >> 3);
  const int rowblk = swz & 63, split = swz >> 6;
  const int arowb = rowblk * BM + w * 32;

  // A fragments: 32 rows x 256 K in registers for the whole block.
  bfrag_t a[2][KC];
#pragma unroll
  for (int mf = 0; mf < 2; ++mf) {
    const int ar = arowb + mf * 16 + l15;
#pragma unroll
    for (int kc = 0; kc < KC; ++kc)
      a[mf][kc] = *reinterpret_cast<const bfrag_t*>(
          zn + (size_t)ar * D_ + kc * 32 + l4 * 8);
  }

  labbuf[tid]       = labels[(split * CPS + tid) & (B_ - 1)];
  labbuf[tid + 256] = labels[(split * CPS + tid + 256) & (B_ - 1)];

  int labR[2][4];
#pragma unroll
  for (int mf = 0; mf < 2; ++mf)
#pragma unroll
    for (int rg = 0; rg < 4; ++rg)
      labR[mf][rg] = labels[(arowb + mf * 16 + l4 * 4 + rg) & (B_ - 1)];

  float Srun[2][4];
#pragma unroll
  for (int mf = 0; mf < 2; ++mf)
#pragma unroll
    for (int rg = 0; rg < 4; ++rg) Srun[mf][rg] = 0.f;

  // hoisted addressing ----------------------------------------------------
  const int offp0 = l15 * 512 + ((l4 ^ (l15 & 7)) << 4);
  const int offp1 = l15 * 512 + (((4 + l4) ^ (l15 & 7)) << 4);
  uint so[4];
#pragma unroll
  for (int q = 0; q < 4; ++q) {
    const int rw = w * 8 + q * 2 + lh;
    so[q] = rw * 32 + (c31 ^ (rw & 7));
  }
  const uint4* gsplit =
      reinterpret_cast<const uint4*>(zn) + (size_t)(split * CPS) * 32;
  const char* lb0 = (const char*)lds16;
  const char* lb1 = (const char*)lds16 + (1 << 14);

  auto stage = [&](int t, int bufsel) {
    const uint4* gt = gsplit + t * (BN * 32);
    uint4* db = lds16 + bufsel * (BN * 32) + w * 256;
#pragma unroll
    for (int q = 0; q < 4; ++q) cp16_lds(gt + so[q], db + q * 64);
  };

  auto mfma_tile = [&](const char* lb, f32x4_t (&acc)[2][2]) {
#pragma unroll
    for (int mf = 0; mf < 2; ++mf)
#pragma unroll
      for (int nf = 0; nf < 2; ++nf)
        acc[mf][nf] = (f32x4_t){0.f, 0.f, 0.f, 0.f};
#pragma unroll
    for (int kc = 0; kc < KC; ++kc) {
      const int kimm = (kc >> 1) << 7;
      const int po = (kc & 1) ? offp1 : offp0;
#pragma unroll
      for (int nf = 0; nf < 2; ++nf) {
        bfrag_t bf = *reinterpret_cast<const bfrag_t*>(lb + po + nf * 8192 + kimm);
        acc[0][nf] = __builtin_amdgcn_mfma_f32_16x16x32_bf16(a[0][kc], bf, acc[0][nf], 0, 0, 0);
        acc[1][nf] = __builtin_amdgcn_mfma_f32_16x16x32_bf16(a[1][kc], bf, acc[1][nf], 0, 0, 0);
      }
    }
  };

  // fixed-max epilogue for a finished tile: S += exp(sim*2 - 2), label-masked
  auto epi = [&](int ct, f32x4_t (&acc)[2][2]) {
    const int lc0 = labbuf[ct * BN + l15];
    const int lc1 = labbuf[ct * BN + 16 + l15];
#pragma unroll
    for (int mf = 0; mf < 2; ++mf) {
#pragma unroll
      for (int rg = 0; rg < 4; ++rg) {
        const int rl = labR[mf][rg];
        float t0 = fmaf(acc[mf][0][rg], 2.0f * LOG2E, -2.0f * LOG2E);
        float t1 = fmaf(acc[mf][1][rg], 2.0f * LOG2E, -2.0f * LOG2E);
        float e0 = __builtin_amdgcn_exp2f(t0);
        float e1 = __builtin_amdgcn_exp2f(t1);
        e0 = (lc0 != rl) ? e0 : 0.0f;
        e1 = (lc1 != rl) ? e1 : 0.0f;
        Srun[mf][rg] += e0 + e1;
      }
    }
  };

  f32x4_t accA[2][2], accB[2][2];

  // pipeline: MFMA(ct) overlaps epi(ct-1); barrier per tile as before.
  stage(0, 0);
  __syncthreads();                 // buf0 + labbuf ready
  stage(1, 1);
  mfma_tile(lb0, accA);            // tile 0
  __syncthreads();                 // drains stage(1)

#pragma unroll
  for (int c2 = 0; c2 < (NT_ - 2) / 2; ++c2) {   // 7 pairs: tiles 1..14
    const int ct = 1 + 2 * c2;
    stage(ct + 1, 0);              // refill buf0 (tile ct-1's readers done)
    mfma_tile(lb1, accB);          // tile ct   (odd -> buf1)
    epi(ct - 1, accA);             // overlapped VALU
    __syncthreads();
    stage(ct + 2, 1);              // ct+2 <= 15 always in this loop
    mfma_tile(lb0, accA);          // tile ct+1 (even -> buf0)
    epi(ct, accB);
    __syncthreads();
  }
  mfma_tile(lb1, accB);            // tile 15
  epi(NT_ - 2, accA);
  epi(NT_ - 1, accB);

  // cross-lane (16 cols) sum, one write per row per split
#pragma unroll
  for (int mf = 0; mf < 2; ++mf) {
#pragma unroll
    for (int rg = 0; rg < 4; ++rg) {
      float s = Srun[mf][rg];
#pragma unroll
      for (int d = 1; d < 16; d <<= 1) s += __shfl_xor(s, d);
      if (l15 == 0)
        Spart[(size_t)split * N_ + arowb + mf * 16 + l4 * 4 + rg] = s;
    }
  }
}

// ---------------- finalize: 32 blocks, atomic ----------------
__global__ __launch_bounds__(256) void k_finalize(
    const float* __restrict__ Spart, const float* __restrict__ pos,
    float* __restrict__ out) {
  __shared__ float red[4];
  const int i = blockIdx.x * 256 + threadIdx.x;
  const float p = pos[i];
  float S = __builtin_amdgcn_exp2f(fmaf(p, LOG2E, -2.0f * LOG2E));  // exp(p-2)
#pragma unroll
  for (int s = 0; s < SPLITS; ++s) S += Spart[s * N_ + i];
  float c = 2.0f + __logf(S) - p;   // lse_i - pos_i
#pragma unroll
  for (int d = 1; d < 64; d <<= 1) c += __shfl_xor(c, d);
  const int w = threadIdx.x >> 6, lane = threadIdx.x & 63;
  if (lane == 0) red[w] = c;
  __syncthreads();
  if (threadIdx.x == 0) {
    float t = red[0] + red[1] + red[2] + red[3];
    atomicAdd(out, t * (1.0f / (float)N_));
  }
}

extern "C" void kernel_launch(void* const* d_in, const int* in_sizes, int n_in,
                              void* d_out, int out_size, void* d_ws, size_t ws_size,
                              hipStream_t stream) {
  (void)in_sizes; (void)n_in; (void)out_size; (void)ws_size;
  const float* zi = (const float*)d_in[0];
  const float* zj = (const float*)d_in[1];
  const int* labels = (const int*)d_in[2];
  char* ws = (char*)d_ws;
  ushort* zn   = (ushort*)(ws);                               // 4 MB
  float* pos   = (float*)(ws + 4u * 1024 * 1024);             // 32 KB
  float* Spart = (float*)(ws + 4u * 1024 * 1024 + 32 * 1024); // 512 KB
  float* out = (float*)d_out;

  k_prep<<<B_ / 4, 256, 0, stream>>>(zi, zj, zn, pos, out);
  k_flash<<<(N_ / BM) * SPLITS, 256, 0, stream>>>(zn, labels, Spart);
  k_finalize<<<N_ / 256, 256, 0, stream>>>(Spart, pos, out);
}

// Round 6
// 134.405 us; speedup vs baseline: 2.4771x; 1.2219x over previous
//
#include <hip/hip_runtime.h>
#include <hip/hip_bf16.h>

// NT-Xent loss, MI355X, round 6.
// r4/r5 regression was alloca'd acc arrays (lambdas + arrays-by-ref) ->
// scratch spill traffic (100-400MB). This round: named acc scalars + macros,
// 3-buffer LDS with counted vmcnt(4) + raw s_barrier (T3/T4), pipelined
// epilogue (MFMA of tile ct || exp-epilogue of tile ct-1).

#define B_ 4096
#define N_ 8192
#define D_ 256
#define EPS_ 1e-8f
#define SPLITS 16
#define BM 128              // rows per block (4 waves x 32 rows)
#define BN 32               // cols per LDS tile
#define KC 8                // D/32 k-chunks
#define CPS (N_ / SPLITS)   // 512 cols per split
#define NT_ (CPS / BN)      // 16 tiles per split
#define LOG2E 1.44269504088896340736f
#define K2L  (2.0f * LOG2E)
#define NK2L (-2.0f * LOG2E)

typedef __attribute__((ext_vector_type(8))) short bfrag_t;   // 8 bf16
typedef __attribute__((ext_vector_type(4))) float f32x4_t;   // MFMA C/D

__device__ __forceinline__ ushort f2bf_rne(float x) {
  union { float f; unsigned u; } a; a.f = x;
  unsigned r = a.u + 0x7FFFu + ((a.u >> 16) & 1u);
  return (ushort)(r >> 16);
}

__device__ __forceinline__ void cp16_lds(const uint4* g, uint4* l) {
  __builtin_amdgcn_global_load_lds(
      (const __attribute__((address_space(1))) unsigned int*)g,
      (__attribute__((address_space(3))) unsigned int*)l, 16, 0, 0);
}

// ---------------- fused normalize + positives: one wave per pair ----------------
__global__ __launch_bounds__(256) void k_prep(
    const float* __restrict__ zi, const float* __restrict__ zj,
    ushort* __restrict__ zn, float* __restrict__ pos, float* __restrict__ out) {
  if (blockIdx.x == 0 && threadIdx.x == 0) out[0] = 0.0f;  // for finalize atomics
  const int w = threadIdx.x >> 6, lane = threadIdx.x & 63;
  const int p = blockIdx.x * 4 + w;
  float4 a = reinterpret_cast<const float4*>(zi + (size_t)p * D_)[lane];
  float4 b = reinterpret_cast<const float4*>(zj + (size_t)p * D_)[lane];
  float si = a.x * a.x + a.y * a.y + a.z * a.z + a.w * a.w;
  float sj = b.x * b.x + b.y * b.y + b.z * b.z + b.w * b.w;
  float dd = a.x * b.x + a.y * b.y + a.z * b.z + a.w * b.w;
#pragma unroll
  for (int d = 1; d < 64; d <<= 1) {
    si += __shfl_xor(si, d);
    sj += __shfl_xor(sj, d);
    dd += __shfl_xor(dd, d);
  }
  const float ni = fmaxf(sqrtf(si), EPS_), nj = fmaxf(sqrtf(sj), EPS_);
  const float ii = 1.0f / ni, ij = 1.0f / nj;
  ushort4 oi, oj;
  oi.x = f2bf_rne(a.x * ii); oi.y = f2bf_rne(a.y * ii);
  oi.z = f2bf_rne(a.z * ii); oi.w = f2bf_rne(a.w * ii);
  oj.x = f2bf_rne(b.x * ij); oj.y = f2bf_rne(b.y * ij);
  oj.z = f2bf_rne(b.z * ij); oj.w = f2bf_rne(b.w * ij);
  reinterpret_cast<ushort4*>(zn + (size_t)p * D_)[lane] = oi;
  reinterpret_cast<ushort4*>(zn + (size_t)(p + B_) * D_)[lane] = oj;
  if (lane == 0) {
    float v = dd / (ni * nj) * 2.0f;   // /T with T=0.5
    pos[p] = v;
    pos[p + B_] = v;
  }
}

// tile ct's MFMAs: 16 x 16x16x32 into 4 named f32x4 accs
#define MFMA_TILE(LB, C0, C1, C2, C3)                                          \
  {                                                                            \
    C0 = (f32x4_t){0.f, 0.f, 0.f, 0.f}; C1 = (f32x4_t){0.f, 0.f, 0.f, 0.f};   \
    C2 = (f32x4_t){0.f, 0.f, 0.f, 0.f}; C3 = (f32x4_t){0.f, 0.f, 0.f, 0.f};   \
    _Pragma("unroll")                                                          \
    for (int kc = 0; kc < KC; ++kc) {                                          \
      const int po = (kc & 1) ? offp1 : offp0;                                 \
      const int ki = (kc >> 1) << 7;                                           \
      bfrag_t b0 = *reinterpret_cast<const bfrag_t*>((LB) + po + ki);          \
      bfrag_t b1 = *reinterpret_cast<const bfrag_t*>((LB) + po + 8192 + ki);   \
      C0 = __builtin_amdgcn_mfma_f32_16x16x32_bf16(a[0][kc], b0, C0, 0, 0, 0); \
      C2 = __builtin_amdgcn_mfma_f32_16x16x32_bf16(a[1][kc], b0, C2, 0, 0, 0); \
      C1 = __builtin_amdgcn_mfma_f32_16x16x32_bf16(a[0][kc], b1, C1, 0, 0, 0); \
      C3 = __builtin_amdgcn_mfma_f32_16x16x32_bf16(a[1][kc], b1, C3, 0, 0, 0); \
    }                                                                          \
  }

// fixed-max epilogue of a finished tile: S += exp(sim*2 - 2), label-masked.
// C0:(mf0,nf0) C1:(mf0,nf1) C2:(mf1,nf0) C3:(mf1,nf1)
#define EPI(CT, C0, C1, C2, C3)                                                \
  {                                                                            \
    const int lc0 = labbuf[(CT) * BN + l15];                                   \
    const int lc1 = labbuf[(CT) * BN + 16 + l15];                              \
    _Pragma("unroll")                                                          \
    for (int rg = 0; rg < 4; ++rg) {                                           \
      const int rl0 = labR[0][rg], rl1 = labR[1][rg];                          \
      float e0 = __builtin_amdgcn_exp2f(fmaf(C0[rg], K2L, NK2L));              \
      float e1 = __builtin_amdgcn_exp2f(fmaf(C1[rg], K2L, NK2L));              \
      float e2 = __builtin_amdgcn_exp2f(fmaf(C2[rg], K2L, NK2L));              \
      float e3 = __builtin_amdgcn_exp2f(fmaf(C3[rg], K2L, NK2L));              \
      e0 = (lc0 != rl0) ? e0 : 0.0f;                                           \
      e1 = (lc1 != rl0) ? e1 : 0.0f;                                           \
      e2 = (lc0 != rl1) ? e2 : 0.0f;                                           \
      e3 = (lc1 != rl1) ? e3 : 0.0f;                                           \
      Srun[0][rg] += e0 + e1;                                                  \
      Srun[1][rg] += e2 + e3;                                                  \
    }                                                                          \
  }

// counted-vmcnt barrier: newest N loads may stay in flight across it
#define WAITB(N)                                                               \
  do {                                                                         \
    __builtin_amdgcn_sched_barrier(0);                                         \
    asm volatile("s_waitcnt vmcnt(" #N ")" ::: "memory");                      \
    __builtin_amdgcn_s_barrier();                                              \
    __builtin_amdgcn_sched_barrier(0);                                         \
  } while (0)

// ---------------- flash LSE (fixed max = 2), 3-buffer pipelined ----------------
__global__ __launch_bounds__(256) void k_flash(
    const ushort* __restrict__ zn, const int* __restrict__ labels,
    float* __restrict__ Spart) {
  __shared__ uint4 lds16[3 * BN * 32];   // 3 x 16KB tile buffers, swizzled
  __shared__ int labbuf[CPS];            // this split's column labels, 2KB
  const int tid = threadIdx.x;
  const int w = tid >> 6, lane = tid & 63;
  const int l15 = lane & 15, l4 = lane >> 4;
  const int c31 = lane & 31, lh = lane >> 5;

  // XCD-aware bijective swizzle: XCD x gets splits {2x,2x+1} x 64 row-blocks
  const int bid = blockIdx.x;
  const int swz = (bid & 7) * 128 + (bid >> 3);
  const int rowblk = swz & 63, split = swz >> 6;
  const int arowb = rowblk * BM + w * 32;

  // A fragments: 32 rows x 256 K in registers for the whole block.
  bfrag_t a[2][KC];
#pragma unroll
  for (int mf = 0; mf < 2; ++mf) {
    const int ar = arowb + mf * 16 + l15;
#pragma unroll
    for (int kc = 0; kc < KC; ++kc)
      a[mf][kc] = *reinterpret_cast<const bfrag_t*>(
          zn + (size_t)ar * D_ + kc * 32 + l4 * 8);
  }

  labbuf[tid]       = labels[(split * CPS + tid) & (B_ - 1)];
  labbuf[tid + 256] = labels[(split * CPS + tid + 256) & (B_ - 1)];

  int labR[2][4];
#pragma unroll
  for (int mf = 0; mf < 2; ++mf)
#pragma unroll
    for (int rg = 0; rg < 4; ++rg)
      labR[mf][rg] = labels[(arowb + mf * 16 + l4 * 4 + rg) & (B_ - 1)];

  float Srun[2][4];
#pragma unroll
  for (int mf = 0; mf < 2; ++mf)
#pragma unroll
    for (int rg = 0; rg < 4; ++rg) Srun[mf][rg] = 0.f;

  // hoisted addressing ----------------------------------------------------
  const int offp0 = l15 * 512 + ((l4 ^ (l15 & 7)) << 4);
  const int offp1 = l15 * 512 + (((4 + l4) ^ (l15 & 7)) << 4);
  uint so[4];
#pragma unroll
  for (int q = 0; q < 4; ++q) {
    const int rw = w * 8 + q * 2 + lh;
    so[q] = rw * 32 + (c31 ^ (rw & 7));
  }
  const uint4* gsplit =
      reinterpret_cast<const uint4*>(zn) + (size_t)(split * CPS) * 32;
  const char* lb0 = (const char*)lds16;
  const char* lb1 = (const char*)lds16 + 16384;
  const char* lb2 = (const char*)lds16 + 32768;

  auto stage = [&](int t, int bufsel) {
    const uint4* gt = gsplit + t * (BN * 32);
    uint4* db = lds16 + bufsel * (BN * 32) + w * 256;
#pragma unroll
    for (int q = 0; q < 4; ++q) cp16_lds(gt + so[q], db + q * 64);
  };

  f32x4_t cA0, cA1, cA2, cA3, cB0, cB1, cB2, cB3;

  // prologue: tiles 0,1 staged; full drain once (also covers labbuf/A-loads)
  stage(0, 0); stage(1, 1);
  __syncthreads();

  // tile 0 (buf0 -> accA)
  stage(2, 2);
  MFMA_TILE(lb0, cA0, cA1, cA2, cA3);
  WAITB(4);

  // steady state: stage(ct+2), MFMA(ct), EPI(ct-1), counted barrier
  stage(3, 0);  MFMA_TILE(lb1, cB0, cB1, cB2, cB3); EPI(0,  cA0, cA1, cA2, cA3); WAITB(4);
  stage(4, 1);  MFMA_TILE(lb2, cA0, cA1, cA2, cA3); EPI(1,  cB0, cB1, cB2, cB3); WAITB(4);
  stage(5, 2);  MFMA_TILE(lb0, cB0, cB1, cB2, cB3); EPI(2,  cA0, cA1, cA2, cA3); WAITB(4);
  stage(6, 0);  MFMA_TILE(lb1, cA0, cA1, cA2, cA3); EPI(3,  cB0, cB1, cB2, cB3); WAITB(4);
  stage(7, 1);  MFMA_TILE(lb2, cB0, cB1, cB2, cB3); EPI(4,  cA0, cA1, cA2, cA3); WAITB(4);
  stage(8, 2);  MFMA_TILE(lb0, cA0, cA1, cA2, cA3); EPI(5,  cB0, cB1, cB2, cB3); WAITB(4);
  stage(9, 0);  MFMA_TILE(lb1, cB0, cB1, cB2, cB3); EPI(6,  cA0, cA1, cA2, cA3); WAITB(4);
  stage(10, 1); MFMA_TILE(lb2, cA0, cA1, cA2, cA3); EPI(7,  cB0, cB1, cB2, cB3); WAITB(4);
  stage(11, 2); MFMA_TILE(lb0, cB0, cB1, cB2, cB3); EPI(8,  cA0, cA1, cA2, cA3); WAITB(4);
  stage(12, 0); MFMA_TILE(lb1, cA0, cA1, cA2, cA3); EPI(9,  cB0, cB1, cB2, cB3); WAITB(4);
  stage(13, 1); MFMA_TILE(lb2, cB0, cB1, cB2, cB3); EPI(10, cA0, cA1, cA2, cA3); WAITB(4);
  stage(14, 2); MFMA_TILE(lb0, cA0, cA1, cA2, cA3); EPI(11, cB0, cB1, cB2, cB3); WAITB(4);
  stage(15, 0); MFMA_TILE(lb1, cB0, cB1, cB2, cB3); EPI(12, cA0, cA1, cA2, cA3); WAITB(4);
  // tile 14: no stage(16); need tile 15 fully landed -> vmcnt(0)
  MFMA_TILE(lb2, cA0, cA1, cA2, cA3); EPI(13, cB0, cB1, cB2, cB3); WAITB(0);
  // tile 15: last, no barrier
  MFMA_TILE(lb0, cB0, cB1, cB2, cB3); EPI(14, cA0, cA1, cA2, cA3);
  EPI(15, cB0, cB1, cB2, cB3);

  // cross-lane (16 cols) sum, one write per row per split
#pragma unroll
  for (int mf = 0; mf < 2; ++mf) {
#pragma unroll
    for (int rg = 0; rg < 4; ++rg) {
      float s = Srun[mf][rg];
#pragma unroll
      for (int d = 1; d < 16; d <<= 1) s += __shfl_xor(s, d);
      if (l15 == 0)
        Spart[(size_t)split * N_ + arowb + mf * 16 + l4 * 4 + rg] = s;
    }
  }
}

// ---------------- finalize: 32 blocks, atomic ----------------
__global__ __launch_bounds__(256) void k_finalize(
    const float* __restrict__ Spart, const float* __restrict__ pos,
    float* __restrict__ out) {
  __shared__ float red[4];
  const int i = blockIdx.x * 256 + threadIdx.x;
  const float p = pos[i];
  float S = __builtin_amdgcn_exp2f(fmaf(p, LOG2E, NK2L));  // exp(p-2)
#pragma unroll
  for (int s = 0; s < SPLITS; ++s) S += Spart[s * N_ + i];
  float c = 2.0f + __logf(S) - p;   // lse_i - pos_i
#pragma unroll
  for (int d = 1; d < 64; d <<= 1) c += __shfl_xor(c, d);
  const int w = threadIdx.x >> 6, lane = threadIdx.x & 63;
  if (lane == 0) red[w] = c;
  __syncthreads();
  if (threadIdx.x == 0) {
    float t = red[0] + red[1] + red[2] + red[3];
    atomicAdd(out, t * (1.0f / (float)N_));
  }
}

extern "C" void kernel_launch(void* const* d_in, const int* in_sizes, int n_in,
                              void* d_out, int out_size, void* d_ws, size_t ws_size,
                              hipStream_t stream) {
  (void)in_sizes; (void)n_in; (void)out_size; (void)ws_size;
  const float* zi = (const float*)d_in[0];
  const float* zj = (const float*)d_in[1];
  const int* labels = (const int*)d_in[2];
  char* ws = (char*)d_ws;
  ushort* zn   = (ushort*)(ws);                               // 4 MB
  float* pos   = (float*)(ws + 4u * 1024 * 1024);             // 32 KB
  float* Spart = (float*)(ws + 4u * 1024 * 1024 + 32 * 1024); // 512 KB
  float* out = (float*)d_out;

  k_prep<<<B_ / 4, 256, 0, stream>>>(zi, zj, zn, pos, out);
  k_flash<<<(N_ / BM) * SPLITS, 256, 0, stream>>>(zn, labels, Spart);
  k_finalize<<<N_ / 256, 256, 0, stream>>>(Spart, pos, out);
}